// Round 5
// baseline (277.438 us; speedup 1.0000x reference)
//
#include <hip/hip_runtime.h>

// GuidedFilterND: I (8,4,768,768) f32 guide, p (8,1,768,768) f32 input, r=8, eps=1e-4.
// Stage A: box-filter 19 product channels, per-pixel 4x4 SPD solve -> (As,b) float2 + sumI (ws)
// Stage B: box-filter (As,b); q = (f(As)*sumI + f(b)) / N
// Round 10: stage A is LDS-PIPE-THROUGHPUT-bound (45 ds_*_b128/row/wave x 12cy
//   = ~75% of the per-CU DS pipe; VALU 46%, HBM 28% are shadows of it; occupancy
//   was a red herring -- the grid only supplies 16 waves/CU). Fix: amortize the
//   horizontal tree over 2x outputs: each lane owns 2 adjacent columns.
//   Publish pair-sum P + raw lo,hi (15W); in-place S4P over P (15R+5W); outputs:
//     even col c=cb+2t:  S4P[t-4] + S4P[t](reg) + lo[t+4]
//     odd  col c=cb+2t+1: hi[t-4] + S4P[t-3] + S4P[t+1]
//   = 60 DS-inst/row per 96 outputs (0.625/out) vs 45 per 48 (0.94/out): 1.5x cut.
//   TA=64 (1 wave), SHA=16, LDS 15.4KB -> 10 waves/CU (fine: DS-bound, not occ-bound).
//   Stage B: round-9 version unchanged (passed).

#define HH 768
#define WW 768
#define CC 4
#define BB 8
#define RR 8
#define EPSF 1.0e-4f

// ---- stage A geometry: 1 wave/block, 2 cols/lane, pair tree ----
#define TA 64
#define LN 64
#define OUTA 96              // output cols per wave (lanes 4..51, 2 each)
#define NBANDA (WW / OUTA)   // 8
#define SHA 16
#define NSTRIPEA (HH / SHA)  // 48

// ---- stage B geometry (round-9 proven) ----
#define TB 128
#define OUTB 48              // output cols per wave
#define SUPERB (2 * OUTB)    // 96 per block
#define NBANDB (WW / SUPERB) // 8
#define SHB 8
#define NSTRIPEB (HH / SHB)  // 96

// Intra-wave LDS sync: wait this wave's own LDS ops (lgkm only; no vmcnt drain).
// "memory" clobber = compiler fence: no LDS access may be moved across it.
__device__ __forceinline__ void wave_lds_sync() {
  asm volatile("s_waitcnt lgkmcnt(0)" ::: "memory");
}

template<bool ADD>
__device__ __forceinline__ float accum_col(const float* __restrict__ Ib,
                                           const float* __restrict__ pb,
                                           int row, int col,
                                           float* __restrict__ s) {
  const int off = row * WW + col;
  const int chs = HH * WW;
  float i0 = Ib[off];
  float i1 = Ib[chs + off];
  float i2 = Ib[2 * chs + off];
  float i3 = Ib[3 * chs + off];
  float pv = pb[off];
  float pr[19];
  pr[0] = i0; pr[1] = i1; pr[2] = i2; pr[3] = i3;
  pr[4] = pv;
  pr[5] = pv * i0; pr[6] = pv * i1; pr[7] = pv * i2; pr[8] = pv * i3;
  pr[9]  = i0 * i0; pr[10] = i0 * i1; pr[11] = i0 * i2; pr[12] = i0 * i3;
  pr[13] = i1 * i1; pr[14] = i1 * i2; pr[15] = i1 * i3;
  pr[16] = i2 * i2; pr[17] = i2 * i3;
  pr[18] = i3 * i3;
#pragma unroll
  for (int k = 0; k < 19; ++k) {
    if (ADD) s[k] += pr[k]; else s[k] -= pr[k];
  }
  return i0 + i1 + i2 + i3;
}

__device__ __forceinline__ float2 gf_solve(const float* __restrict__ h, float invN) {
  float Im0 = h[0] * invN, Im1 = h[1] * invN, Im2 = h[2] * invN, Im3 = h[3] * invN;
  float pm = h[4] * invN;
  float ft0 = h[5] * invN - pm * Im0;
  float ft1 = h[6] * invN - pm * Im1;
  float ft2 = h[7] * invN - pm * Im2;
  float ft3 = h[8] * invN - pm * Im3;
  float m[4][4];
  m[0][0] = h[9]  * invN + EPSF;
  m[0][1] = h[10] * invN;
  m[0][2] = h[11] * invN;
  m[0][3] = h[12] * invN;
  m[1][1] = h[13] * invN + EPSF;
  m[1][2] = h[14] * invN;
  m[1][3] = h[15] * invN;
  m[2][2] = h[16] * invN + EPSF;
  m[2][3] = h[17] * invN;
  m[3][3] = h[18] * invN + EPSF;
  m[1][0] = m[0][1]; m[2][0] = m[0][2]; m[3][0] = m[0][3];
  m[2][1] = m[1][2]; m[3][1] = m[1][3]; m[3][2] = m[2][3];
  float y[4] = {1.0f, 1.0f, 1.0f, 1.0f};
#pragma unroll
  for (int k = 0; k < 4; ++k) {
    float piv = 1.0f / m[k][k];
#pragma unroll
    for (int j = 0; j < 4; ++j) m[k][j] *= piv;
    y[k] *= piv;
#pragma unroll
    for (int i = 0; i < 4; ++i) {
      if (i == k) continue;
      float f = m[i][k];
#pragma unroll
      for (int j = 0; j < 4; ++j) m[i][j] -= f * m[k][j];
      y[i] -= f * y[k];
    }
  }
  float Asum = ft0 * y[0] + ft1 * y[1] + ft2 * y[2] + ft3 * y[3];
  float bv = pm - Asum * (Im0 + Im1 + Im2 + Im3);
  return make_float2(Asum, bv);
}

__global__ __launch_bounds__(TA, 4) void gf_stageA(const float* __restrict__ I,
                                                   const float* __restrict__ p,
                                                   float2* __restrict__ AB,
                                                   float* __restrict__ sumI_ws,
                                                   int storeSum) {
  // three 20-float slots per lane: SP (pair sums -> S4P in place), SL (lo), SH (hi)
  __shared__ float SP[LN][20];
  __shared__ float SL[LN][20];
  __shared__ float SH[LN][20];
  const int t = threadIdx.x;
  const int band0 = (int)blockIdx.x * OUTA;   // first output col of this wave
  const int cb = band0 - RR;                  // col base (even, >= -8)
  const int c0 = cb + 2 * t;                  // this lane's even col
  const int c1 = c0 + 1;                      // this lane's odd col
  const bool ok0 = (c0 >= 0) && (c0 < WW);
  const bool ok1 = (c1 >= 0) && (c1 < WW);
  const int r0 = (int)blockIdx.y * SHA;
  const int batch = (int)blockIdx.z;

  const float* Ib = I + (size_t)batch * CC * HH * WW;
  const float* pb = p + (size_t)batch * HH * WW;
  float* sIb = sumI_ws + (size_t)batch * HH * WW;
  float2* ABb = AB + (size_t)batch * HH * WW;

  float s0[20], s1[20];
#pragma unroll
  for (int k = 0; k < 20; ++k) { s0[k] = 0.0f; s1[k] = 0.0f; }

  // warm-up: preload window of row (r0-1) = rows [r0-RR-1, r0+RR-1] clipped.
  {
    int rlo = r0 - RR - 1; if (rlo < 0) rlo = 0;
    for (int row = rlo; row < r0 + RR; ++row) {
      if (ok0) {
        float f = accum_col<true>(Ib, pb, row, c0, s0);
        if (storeSum && r0 == 0) sIb[row * WW + c0] = f;
      }
      if (ok1) {
        float f = accum_col<true>(Ib, pb, row, c1, s1);
        if (storeSum && r0 == 0) sIb[row * WW + c1] = f;
      }
    }
  }

  // output lanes: t in [4, 51] emit cols c0 (=band0+2t-8) and c1; always in [0,768)
  const bool outok = (t >= 4) && (t <= 51);
  const int nwe = min(c0 + RR, WW - 1) - max(c0 - RR, 0) + 1;
  const int nwo = min(c1 + RR, WW - 1) - max(c1 - RR, 0) + 1;

  for (int r = r0; r < r0 + SHA; ++r) {
    // vertical running-sum update for both columns
    {
      int rl = r + RR;
      if (rl < HH) {
        if (ok0) {
          float f = accum_col<true>(Ib, pb, rl, c0, s0);
          if (storeSum) sIb[rl * WW + c0] = f;
        }
        if (ok1) {
          float f = accum_col<true>(Ib, pb, rl, c1, s1);
          if (storeSum) sIb[rl * WW + c1] = f;
        }
      }
      int rt = r - RR - 1;
      if (rt >= 0) {
        if (ok0) accum_col<false>(Ib, pb, rt, c0, s0);
        if (ok1) accum_col<false>(Ib, pb, rt, c1, s1);
      }
    }
    // pair sums in registers
    float P[20];
#pragma unroll
    for (int k = 0; k < 20; ++k) P[k] = s0[k] + s1[k];

    // phase 0: publish P, lo, hi (15 x b128)
    {
      float4* wp = (float4*)(&SP[t][0]);
      float4* wl = (float4*)(&SL[t][0]);
      float4* wh = (float4*)(&SH[t][0]);
#pragma unroll
      for (int j = 0; j < 5; ++j) {
        wp[j] = make_float4(P[4*j], P[4*j+1], P[4*j+2], P[4*j+3]);
        wl[j] = make_float4(s0[4*j], s0[4*j+1], s0[4*j+2], s0[4*j+3]);
        wh[j] = make_float4(s1[4*j], s1[4*j+1], s1[4*j+2], s1[4*j+3]);
      }
    }
    wave_lds_sync();

    // phase 1: S4P[t] = P[t]+P[t+1]+P[t+2]+P[t+3], written IN PLACE over SP[t].
    // Cross-lane safe: per float4 group, all reads are issued before the write
    // (write value depends on the reads -> dataflow order; per-wave DS pipe FIFO).
    float S4[20];
#pragma unroll
    for (int k = 0; k < 20; ++k) S4[k] = 0.0f;
    if (t < LN - 3) {
      const float4* a1 = (const float4*)(&SP[t + 1][0]);
      const float4* a2 = (const float4*)(&SP[t + 2][0]);
      const float4* a3 = (const float4*)(&SP[t + 3][0]);
      float4* wp = (float4*)(&SP[t][0]);
#pragma unroll
      for (int j = 0; j < 5; ++j) {
        float4 xa = a1[j];
        float4 xb = a2[j];
        float4 xc = a3[j];
        float4 o;
        o.x = P[4*j + 0] + xa.x + xb.x + xc.x;
        o.y = P[4*j + 1] + xa.y + xb.y + xc.y;
        o.z = P[4*j + 2] + xa.z + xb.z + xc.z;
        o.w = P[4*j + 3] + xa.w + xb.w + xc.w;
        wp[j] = o;
        S4[4*j + 0] = o.x; S4[4*j + 1] = o.y; S4[4*j + 2] = o.z; S4[4*j + 3] = o.w;
      }
    }
    wave_lds_sync();

    // phase 2: two outputs per lane (25 reads total)
    if (outok) {
      // even col c0: window [c0-8, c0+8] = S4P[t-4] + S4P[t](reg) + lo[t+4]
      float2 eo, oo;
      {
        const float4* m4 = (const float4*)(&SP[t - 4][0]);
        const float4* l4 = (const float4*)(&SL[t + 4][0]);
        float he[20];
#pragma unroll
        for (int j = 0; j < 5; ++j) {
          float4 a = m4[j];
          float4 b = l4[j];
          he[4*j + 0] = a.x + S4[4*j + 0] + b.x;
          he[4*j + 1] = a.y + S4[4*j + 1] + b.y;
          he[4*j + 2] = a.z + S4[4*j + 2] + b.z;
          he[4*j + 3] = a.w + S4[4*j + 3] + b.w;
        }
        const int nh = min(r + RR, HH - 1) - max(r - RR, 0) + 1;
        eo = gf_solve(he, 1.0f / (float)(nh * nwe));
      }
      // odd col c1: window [c1-8, c1+8] = hi[t-4] + S4P[t-3] + S4P[t+1]
      {
        const float4* q3 = (const float4*)(&SP[t - 3][0]);
        const float4* q1 = (const float4*)(&SP[t + 1][0]);
        const float4* h4 = (const float4*)(&SH[t - 4][0]);
        float ho[20];
#pragma unroll
        for (int j = 0; j < 5; ++j) {
          float4 a = q3[j];
          float4 b = q1[j];
          float4 c = h4[j];
          ho[4*j + 0] = a.x + b.x + c.x;
          ho[4*j + 1] = a.y + b.y + c.y;
          ho[4*j + 2] = a.z + b.z + c.z;
          ho[4*j + 3] = a.w + b.w + c.w;
        }
        const int nh = min(r + RR, HH - 1) - max(r - RR, 0) + 1;
        oo = gf_solve(ho, 1.0f / (float)(nh * nwo));
      }
      // packed store: (A_e, b_e, A_o, b_o) -> one dwordx4 (c0 even => 16B aligned)
      *(float4*)(&ABb[(size_t)r * WW + c0]) = make_float4(eo.x, eo.y, oo.x, oo.y);
    }
    // loop-tail fence: next phase-0 writes must not hoist above phase-2 reads.
    wave_lds_sync();
  }
}

__global__ __launch_bounds__(TB) void gf_stageB(const float* __restrict__ I,
                                                const float2* __restrict__ AB,
                                                const float* __restrict__ sumI_ws,
                                                float* __restrict__ q, int useSum) {
  // per-wave buffer: [lane][row*2+ch], rows 0..7, padded to 20 floats (80 B)
  __shared__ float V[2][LN][20];
  const int tid = threadIdx.x;
  const int wv = tid >> 6;
  const int lane = tid & 63;
  float (*Vw)[20] = V[wv];
  const int band0 = (int)blockIdx.x * SUPERB + wv * OUTB;
  const int r0 = (int)blockIdx.y * SHB;
  const int batch = (int)blockIdx.z;
  const int gc = band0 - RR + lane;
  const bool colok = (gc >= 0 && gc < WW);

  const float2* ABb = AB + (size_t)batch * HH * WW;
  const float* sIb = sumI_ws + (size_t)batch * HH * WW;
  const float* Ib = I + (size_t)batch * CC * HH * WW;

  const int oc = band0 + lane;
  const bool outok = (lane < OUTB) && (oc < WW);
  const int nw = min(oc + RR, WW - 1) - max(oc - RR, 0) + 1;

  // burst-load the whole stripe's AB window: SHB+17 = 25 independent loads (MLP)
  float2 w[SHB + 17];
#pragma unroll
  for (int k = 0; k < SHB + 17; ++k) {
    const int row = r0 - RR - 1 + k;
    const bool ok = colok && (row >= 0) && (row < HH);
    w[k] = ok ? ABb[row * WW + gc] : make_float2(0.0f, 0.0f);
  }
  // burst-load sumI for the stripe's output pixels
  float sm[SHB];
  if (useSum) {
#pragma unroll
    for (int j = 0; j < SHB; ++j)
      sm[j] = outok ? sIb[(r0 + j) * WW + oc] : 0.0f;
  }

  // vertical running sums for ALL 8 rows, kept in registers
  float sA = 0.0f, sB = 0.0f;
#pragma unroll
  for (int k = 0; k < 17; ++k) { sA += w[k].x; sB += w[k].y; }
  float vsA[SHB], vsB[SHB];
#pragma unroll
  for (int j = 0; j < SHB; ++j) {
    sA += w[j + 17].x - w[j].x;
    sB += w[j + 17].y - w[j].y;
    vsA[j] = sA; vsB[j] = sB;
  }
  // pack own raw values: element (2j = A, 2j+1 = B)
  float4 ow[4];
#pragma unroll
  for (int jj = 0; jj < 4; ++jj)
    ow[jj] = make_float4(vsA[2*jj], vsB[2*jj], vsA[2*jj + 1], vsB[2*jj + 1]);

  // phase 0: publish all 8 rows at once (4 x b128)
  float4* vp = (float4*)(&Vw[lane][0]);
#pragma unroll
  for (int jj = 0; jj < 4; ++jj) vp[jj] = ow[jj];
  wave_lds_sync();

  // phase 1: in-place S4 (safe: writes depend on reads via dataflow)
  if (lane < LN - 3) {
    const float4* a1 = (const float4*)(&Vw[lane + 1][0]);
    const float4* a2 = (const float4*)(&Vw[lane + 2][0]);
    const float4* a3 = (const float4*)(&Vw[lane + 3][0]);
    float4 t4v[4];
#pragma unroll
    for (int jj = 0; jj < 4; ++jj) {
      float4 xa = a1[jj];
      float4 xb = a2[jj];
      float4 xc = a3[jj];
      t4v[jj].x = ow[jj].x + xa.x + xb.x + xc.x;
      t4v[jj].y = ow[jj].y + xa.y + xb.y + xc.y;
      t4v[jj].z = ow[jj].z + xa.z + xb.z + xc.z;
      t4v[jj].w = ow[jj].w + xa.w + xb.w + xc.w;
    }
#pragma unroll
    for (int jj = 0; jj < 4; ++jj) vp[jj] = t4v[jj];
  }
  wave_lds_sync();

  // phase 2: h = raw_own + S4[t+1] + S4[t+5] + S4[t+9] + S4[t+13]; emit all 8 rows
  if (outok) {
    const float4* p1  = (const float4*)(&Vw[lane + 1][0]);
    const float4* p5  = (const float4*)(&Vw[lane + 5][0]);
    const float4* p9  = (const float4*)(&Vw[lane + 9][0]);
    const float4* p13 = (const float4*)(&Vw[lane + 13][0]);
    float hA[SHB], hB[SHB];
#pragma unroll
    for (int jj = 0; jj < 4; ++jj) {
      float4 a4 = p1[jj];
      float4 b4 = p5[jj];
      float4 c4 = p9[jj];
      float4 d4 = p13[jj];
      hA[2*jj]     = ow[jj].x + a4.x + b4.x + c4.x + d4.x;
      hB[2*jj]     = ow[jj].y + a4.y + b4.y + c4.y + d4.y;
      hA[2*jj + 1] = ow[jj].z + a4.z + b4.z + c4.z + d4.z;
      hB[2*jj + 1] = ow[jj].w + a4.w + b4.w + c4.w + d4.w;
    }
#pragma unroll
    for (int j = 0; j < SHB; ++j) {
      const int r = r0 + j;
      const int nh = min(r + RR, HH - 1) - max(r - RR, 0) + 1;
      const float invN = 1.0f / (float)(nh * nw);
      float sumI;
      if (useSum) {
        sumI = sm[j];
      } else {
        const int off = r * WW + oc;
        const int chs = HH * WW;
        sumI = Ib[off] + Ib[chs + off] + Ib[2 * chs + off] + Ib[3 * chs + off];
      }
      q[((size_t)batch * HH + r) * WW + oc] = (hA[j] * sumI + hB[j]) * invN;
    }
  }
}

extern "C" void kernel_launch(void* const* d_in, const int* in_sizes, int n_in,
                              void* d_out, int out_size, void* d_ws, size_t ws_size,
                              hipStream_t stream) {
  const float* I = (const float*)d_in[0];   // (8,4,768,768) f32
  const float* p = (const float*)d_in[1];   // (8,1,768,768) f32
  float* q = (float*)d_out;                 // (8,1,768,768) f32

  const size_t npix = (size_t)BB * HH * WW;
  float2* AB = (float2*)d_ws;                               // 37.75 MB
  float* sumI_ws = (float*)(AB + npix);                     // +18.87 MB
  const size_t need = npix * sizeof(float2) + npix * sizeof(float);
  const int useSum = (ws_size >= need) ? 1 : 0;             // constant across calls

  dim3 gridA(NBANDA, NSTRIPEA, BB);    // (8, 48, 8)
  dim3 gridB(NBANDB, NSTRIPEB, BB);    // (8, 96, 8)
  hipLaunchKernelGGL(gf_stageA, gridA, dim3(TA), 0, stream, I, p, AB, sumI_ws, useSum);
  hipLaunchKernelGGL(gf_stageB, gridB, dim3(TB), 0, stream, I, AB, sumI_ws, q, useSum);
}

// Round 6
// 236.347 us; speedup vs baseline: 1.1739x; 1.1739x over previous
//
#include <hip/hip_runtime.h>

// GuidedFilterND: I (8,4,768,768) f32 guide, p (8,1,768,768) f32 input, r=8, eps=1e-4.
// Stage A: box-filter 19 product channels, per-pixel 4x4 SPD solve -> (As,b) float2 + sumI (ws)
// Stage B: box-filter (As,b); q = (f(As)*sumI + f(b)) / N
// Round 11: round-10's 2-col/lane DS cut, with its three latency mistakes fixed:
//   (1) float2 VECTOR loads: 10 loads/row/lane (same as round 9's 1-col version;
//       round 10 did 20 scalar loads -> doubled exposed latency). Pair-granular
//       ok-guard is exact: all pair boundaries are even.
//   (2) SHA=16: 7x48x8 = 2688 blocks = 10.5 waves/CU vs the 10-resident LDS cap
//       (round 10 had 12 supply vs 10 cap -> 2-round tail, 18% occupancy).
//   (3) __launch_bounds__(64,4) caps VGPR at 128 (round 10 drifted to 68+).
//   DS economics: 60 b128/row/wave for 112 outputs = 0.54/out vs round 9's 0.94.
//   DS demand/CU = 10.5 x 16 x 60 x 12cy = 121K cy = 50us @100% -> predict 70-80us.
//   Even col e=cb+2t:  S4P[t-4] + S4P[t](reg) + lo[t+4]     (window [e-8,e+8])
//   Odd  col o=e+1:    hi[t-4] + S4P[t-3] + S4P[t+1]        (window [o-8,o+8])
//   (verified: t=10,cb=-8: even [4,20]=S4P[6]+S4P[10]+lo[14]; odd [5,21]=hi[6]+S4P[7]+S4P[11])
//   Stage B: round-9 version byte-identical (still ~100us, unexplained -- it will
//   outrank stage A in next round's top-5 and finally show its counters).

#define HH 768
#define WW 768
#define CC 4
#define BB 8
#define RR 8
#define EPSF 1.0e-4f

// ---- stage A geometry: 1 wave/block, 2 cols/lane (float2), pair tree ----
#define TA 64
#define LN 64
#define OUTA 112             // output cols per wave (lanes 4..59, 2 each)
#define NBANDA 7             // ceil(768/112)
#define SHA 16
#define NSTRIPEA (HH / SHA)  // 48

// ---- stage B geometry (round-9 proven) ----
#define TB 128
#define OUTB 48              // output cols per wave
#define SUPERB (2 * OUTB)    // 96 per block
#define NBANDB (WW / SUPERB) // 8
#define SHB 8
#define NSTRIPEB (HH / SHB)  // 96

// Intra-wave LDS sync: wait this wave's own LDS ops (lgkm only; no vmcnt drain).
// "memory" clobber = compiler fence: no LDS access may be moved across it.
__device__ __forceinline__ void wave_lds_sync() {
  asm volatile("s_waitcnt lgkmcnt(0)" ::: "memory");
}

// Update both columns' 19-channel vertical sums from one row; returns per-col sumI.
template<bool ADD>
__device__ __forceinline__ float2 accum_pair(const float* __restrict__ Ib,
                                             const float* __restrict__ pb,
                                             int row, int col /*even*/,
                                             float* __restrict__ s0,
                                             float* __restrict__ s1) {
  const int off = row * WW + col;
  const int chs = HH * WW;
  float2 i0 = *(const float2*)(Ib + off);
  float2 i1 = *(const float2*)(Ib + chs + off);
  float2 i2 = *(const float2*)(Ib + 2 * chs + off);
  float2 i3 = *(const float2*)(Ib + 3 * chs + off);
  float2 pv = *(const float2*)(pb + off);
  float pr[19];
  // even column (x lane of the pair)
  pr[0] = i0.x; pr[1] = i1.x; pr[2] = i2.x; pr[3] = i3.x;
  pr[4] = pv.x;
  pr[5] = pv.x * i0.x; pr[6] = pv.x * i1.x; pr[7] = pv.x * i2.x; pr[8] = pv.x * i3.x;
  pr[9]  = i0.x * i0.x; pr[10] = i0.x * i1.x; pr[11] = i0.x * i2.x; pr[12] = i0.x * i3.x;
  pr[13] = i1.x * i1.x; pr[14] = i1.x * i2.x; pr[15] = i1.x * i3.x;
  pr[16] = i2.x * i2.x; pr[17] = i2.x * i3.x;
  pr[18] = i3.x * i3.x;
#pragma unroll
  for (int k = 0; k < 19; ++k) { if (ADD) s0[k] += pr[k]; else s0[k] -= pr[k]; }
  // odd column (y lane of the pair)
  pr[0] = i0.y; pr[1] = i1.y; pr[2] = i2.y; pr[3] = i3.y;
  pr[4] = pv.y;
  pr[5] = pv.y * i0.y; pr[6] = pv.y * i1.y; pr[7] = pv.y * i2.y; pr[8] = pv.y * i3.y;
  pr[9]  = i0.y * i0.y; pr[10] = i0.y * i1.y; pr[11] = i0.y * i2.y; pr[12] = i0.y * i3.y;
  pr[13] = i1.y * i1.y; pr[14] = i1.y * i2.y; pr[15] = i1.y * i3.y;
  pr[16] = i2.y * i2.y; pr[17] = i2.y * i3.y;
  pr[18] = i3.y * i3.y;
#pragma unroll
  for (int k = 0; k < 19; ++k) { if (ADD) s1[k] += pr[k]; else s1[k] -= pr[k]; }
  return make_float2(i0.x + i1.x + i2.x + i3.x, i0.y + i1.y + i2.y + i3.y);
}

__device__ __forceinline__ float2 gf_solve(const float* __restrict__ h, float invN) {
  float Im0 = h[0] * invN, Im1 = h[1] * invN, Im2 = h[2] * invN, Im3 = h[3] * invN;
  float pm = h[4] * invN;
  float ft0 = h[5] * invN - pm * Im0;
  float ft1 = h[6] * invN - pm * Im1;
  float ft2 = h[7] * invN - pm * Im2;
  float ft3 = h[8] * invN - pm * Im3;
  float m[4][4];
  m[0][0] = h[9]  * invN + EPSF;
  m[0][1] = h[10] * invN;
  m[0][2] = h[11] * invN;
  m[0][3] = h[12] * invN;
  m[1][1] = h[13] * invN + EPSF;
  m[1][2] = h[14] * invN;
  m[1][3] = h[15] * invN;
  m[2][2] = h[16] * invN + EPSF;
  m[2][3] = h[17] * invN;
  m[3][3] = h[18] * invN + EPSF;
  m[1][0] = m[0][1]; m[2][0] = m[0][2]; m[3][0] = m[0][3];
  m[2][1] = m[1][2]; m[3][1] = m[1][3]; m[3][2] = m[2][3];
  float y[4] = {1.0f, 1.0f, 1.0f, 1.0f};
#pragma unroll
  for (int k = 0; k < 4; ++k) {
    float piv = 1.0f / m[k][k];
#pragma unroll
    for (int j = 0; j < 4; ++j) m[k][j] *= piv;
    y[k] *= piv;
#pragma unroll
    for (int i = 0; i < 4; ++i) {
      if (i == k) continue;
      float f = m[i][k];
#pragma unroll
      for (int j = 0; j < 4; ++j) m[i][j] -= f * m[k][j];
      y[i] -= f * y[k];
    }
  }
  float Asum = ft0 * y[0] + ft1 * y[1] + ft2 * y[2] + ft3 * y[3];
  float bv = pm - Asum * (Im0 + Im1 + Im2 + Im3);
  return make_float2(Asum, bv);
}

__global__ __launch_bounds__(TA, 4) void gf_stageA(const float* __restrict__ I,
                                                   const float* __restrict__ p,
                                                   float2* __restrict__ AB,
                                                   float* __restrict__ sumI_ws,
                                                   int storeSum) {
  // three 20-float slots per lane (80 B rows): SP (pair sums -> S4P in place),
  // SL (even/lo col sums), SH (odd/hi col sums). b128 access, conflict-free.
  __shared__ float SP[LN][20];
  __shared__ float SL[LN][20];
  __shared__ float SH[LN][20];
  const int t = threadIdx.x;
  const int band0 = (int)blockIdx.x * OUTA;   // first output col of this wave
  const int cb = band0 - 2 * RR / 2 - 8 + 8;  // see below; cb = band0 - 8 (even)
  const int c0 = band0 - 8 + 2 * t;           // this lane's even col
  const bool ok = (c0 >= 0) && (c0 < WW);     // pair-granular: both cols in or out
  const int r0 = (int)blockIdx.y * SHA;
  const int batch = (int)blockIdx.z;
  (void)cb;

  const float* Ib = I + (size_t)batch * CC * HH * WW;
  const float* pb = p + (size_t)batch * HH * WW;
  float* sIb = sumI_ws + (size_t)batch * HH * WW;
  float2* ABb = AB + (size_t)batch * HH * WW;

  float s0[19], s1[19];
#pragma unroll
  for (int k = 0; k < 19; ++k) { s0[k] = 0.0f; s1[k] = 0.0f; }

  // warm-up: preload window of row (r0-1) = rows [r0-RR-1, r0+RR-1] clipped.
  {
    int rlo = r0 - RR - 1; if (rlo < 0) rlo = 0;
    for (int row = rlo; row < r0 + RR; ++row) {
      if (ok) {
        float2 f = accum_pair<true>(Ib, pb, row, c0, s0, s1);
        // rows 0..7 are only ever touched by stripe 0's warm-up: store sumI here
        if (storeSum && r0 == 0)
          *(float2*)(&sIb[row * WW + c0]) = f;
      }
    }
  }

  // output lanes: t in [4,59] emit cols e=band0-8+2t, o=e+1 (= band0 .. band0+111)
  const int ec = c0;                           // even output col for this lane
  const bool outok = (t >= 4) && (t <= 59) && (ec < WW);
  const int nwe = min(ec + RR, WW - 1) - max(ec - RR, 0) + 1;
  const int nwo = min(ec + 1 + RR, WW - 1) - max(ec + 1 - RR, 0) + 1;

  for (int r = r0; r < r0 + SHA; ++r) {
    // vertical rolling update (float2: 10 loads/row total)
    {
      int rl = r + RR;
      if (rl < HH && ok) {
        float2 f = accum_pair<true>(Ib, pb, rl, c0, s0, s1);
        if (storeSum) *(float2*)(&sIb[rl * WW + c0]) = f;
      }
      int rt = r - RR - 1;
      if (rt >= 0 && ok) {
        accum_pair<false>(Ib, pb, rt, c0, s0, s1);
      }
    }
    // pair sums in registers
    float P[20];
#pragma unroll
    for (int k = 0; k < 19; ++k) P[k] = s0[k] + s1[k];
    P[19] = 0.0f;

    // phase 0: publish P, lo(s0), hi(s1): 15 x b128 writes
    float4* wp = (float4*)(&SP[t][0]);
    {
      float4* wl = (float4*)(&SL[t][0]);
      float4* wh = (float4*)(&SH[t][0]);
#pragma unroll
      for (int j = 0; j < 5; ++j) {
        wp[j] = make_float4(P[4*j], P[4*j+1], P[4*j+2], P[4*j+3]);
        wl[j] = make_float4(s0[4*j], s0[4*j+1], s0[4*j+2], s0[4*j+3]);
        wh[j] = make_float4(s1[4*j], s1[4*j+1], s1[4*j+2],
                            (4*j+3 < 19) ? s1[4*j+3] : 0.0f);
      }
    }
    wave_lds_sync();

    // phase 1: S4P[t] = P[t]+P[t+1]+P[t+2]+P[t+3], IN PLACE over SP[t], kept in reg.
    // Per 16B group: all reads issued before the write (write value depends on the
    // reads -> dataflow order; per-wave DS pipe executes in issue order).
    float S4[20];
#pragma unroll
    for (int k = 0; k < 20; ++k) S4[k] = 0.0f;
    if (t < LN - 3) {                          // t <= 60: S4P[60] needed by t=59
      const float4* a1 = (const float4*)(&SP[t + 1][0]);
      const float4* a2 = (const float4*)(&SP[t + 2][0]);
      const float4* a3 = (const float4*)(&SP[t + 3][0]);
#pragma unroll
      for (int j = 0; j < 5; ++j) {
        float4 xa = a1[j];
        float4 xb = a2[j];
        float4 xc = a3[j];
        float4 o;
        o.x = P[4*j + 0] + xa.x + xb.x + xc.x;
        o.y = P[4*j + 1] + xa.y + xb.y + xc.y;
        o.z = P[4*j + 2] + xa.z + xb.z + xc.z;
        o.w = P[4*j + 3] + xa.w + xb.w + xc.w;
        wp[j] = o;
        S4[4*j + 0] = o.x; S4[4*j + 1] = o.y; S4[4*j + 2] = o.z; S4[4*j + 3] = o.w;
      }
    }
    wave_lds_sync();

    // phase 2: two outputs per lane (25 b128 reads)
    if (outok) {
      const int nh = min(r + RR, HH - 1) - max(r - RR, 0) + 1;
      float2 eo, oo;
      {  // even col ec: S4P[t-4] + S4P[t](reg) + lo[t+4]
        const float4* m4 = (const float4*)(&SP[t - 4][0]);
        const float4* l4 = (const float4*)(&SL[t + 4][0]);
        float he[20];
#pragma unroll
        for (int j = 0; j < 5; ++j) {
          float4 a = m4[j];
          float4 b = l4[j];
          he[4*j + 0] = a.x + S4[4*j + 0] + b.x;
          he[4*j + 1] = a.y + S4[4*j + 1] + b.y;
          he[4*j + 2] = a.z + S4[4*j + 2] + b.z;
          he[4*j + 3] = a.w + S4[4*j + 3] + b.w;
        }
        eo = gf_solve(he, 1.0f / (float)(nh * nwe));
      }
      {  // odd col ec+1: hi[t-4] + S4P[t-3] + S4P[t+1]
        const float4* q3 = (const float4*)(&SP[t - 3][0]);
        const float4* q1 = (const float4*)(&SP[t + 1][0]);
        const float4* h4 = (const float4*)(&SH[t - 4][0]);
        float ho[20];
#pragma unroll
        for (int j = 0; j < 5; ++j) {
          float4 a = q3[j];
          float4 b = q1[j];
          float4 c = h4[j];
          ho[4*j + 0] = a.x + b.x + c.x;
          ho[4*j + 1] = a.y + b.y + c.y;
          ho[4*j + 2] = a.z + b.z + c.z;
          ho[4*j + 3] = a.w + b.w + c.w;
        }
        oo = gf_solve(ho, 1.0f / (float)(nh * nwo));
      }
      // packed store: (A_e, b_e, A_o, b_o) -> one dwordx4 (ec even => 16B aligned)
      *(float4*)(&ABb[(size_t)r * WW + ec]) = make_float4(eo.x, eo.y, oo.x, oo.y);
    }
    // loop-tail fence: next phase-0 writes must not hoist above phase-2 reads.
    wave_lds_sync();
  }
}

__global__ __launch_bounds__(TB) void gf_stageB(const float* __restrict__ I,
                                                const float2* __restrict__ AB,
                                                const float* __restrict__ sumI_ws,
                                                float* __restrict__ q, int useSum) {
  // per-wave buffer: [lane][row*2+ch], rows 0..7, padded to 20 floats (80 B)
  __shared__ float V[2][LN][20];
  const int tid = threadIdx.x;
  const int wv = tid >> 6;
  const int lane = tid & 63;
  float (*Vw)[20] = V[wv];
  const int band0 = (int)blockIdx.x * SUPERB + wv * OUTB;
  const int r0 = (int)blockIdx.y * SHB;
  const int batch = (int)blockIdx.z;
  const int gc = band0 - RR + lane;
  const bool colok = (gc >= 0 && gc < WW);

  const float2* ABb = AB + (size_t)batch * HH * WW;
  const float* sIb = sumI_ws + (size_t)batch * HH * WW;
  const float* Ib = I + (size_t)batch * CC * HH * WW;

  const int oc = band0 + lane;
  const bool outok = (lane < OUTB) && (oc < WW);
  const int nw = min(oc + RR, WW - 1) - max(oc - RR, 0) + 1;

  // burst-load the whole stripe's AB window: SHB+17 = 25 independent loads (MLP)
  float2 w[SHB + 17];
#pragma unroll
  for (int k = 0; k < SHB + 17; ++k) {
    const int row = r0 - RR - 1 + k;
    const bool okr = colok && (row >= 0) && (row < HH);
    w[k] = okr ? ABb[row * WW + gc] : make_float2(0.0f, 0.0f);
  }
  // burst-load sumI for the stripe's output pixels
  float sm[SHB];
  if (useSum) {
#pragma unroll
    for (int j = 0; j < SHB; ++j)
      sm[j] = outok ? sIb[(r0 + j) * WW + oc] : 0.0f;
  }

  // vertical running sums for ALL 8 rows, kept in registers
  float sA = 0.0f, sB = 0.0f;
#pragma unroll
  for (int k = 0; k < 17; ++k) { sA += w[k].x; sB += w[k].y; }
  float vsA[SHB], vsB[SHB];
#pragma unroll
  for (int j = 0; j < SHB; ++j) {
    sA += w[j + 17].x - w[j].x;
    sB += w[j + 17].y - w[j].y;
    vsA[j] = sA; vsB[j] = sB;
  }
  // pack own raw values: element (2j = A, 2j+1 = B)
  float4 ow[4];
#pragma unroll
  for (int jj = 0; jj < 4; ++jj)
    ow[jj] = make_float4(vsA[2*jj], vsB[2*jj], vsA[2*jj + 1], vsB[2*jj + 1]);

  // phase 0: publish all 8 rows at once (4 x b128)
  float4* vp = (float4*)(&Vw[lane][0]);
#pragma unroll
  for (int jj = 0; jj < 4; ++jj) vp[jj] = ow[jj];
  wave_lds_sync();

  // phase 1: in-place S4 (safe: writes depend on reads via dataflow)
  if (lane < LN - 3) {
    const float4* a1 = (const float4*)(&Vw[lane + 1][0]);
    const float4* a2 = (const float4*)(&Vw[lane + 2][0]);
    const float4* a3 = (const float4*)(&Vw[lane + 3][0]);
    float4 t4v[4];
#pragma unroll
    for (int jj = 0; jj < 4; ++jj) {
      float4 xa = a1[jj];
      float4 xb = a2[jj];
      float4 xc = a3[jj];
      t4v[jj].x = ow[jj].x + xa.x + xb.x + xc.x;
      t4v[jj].y = ow[jj].y + xa.y + xb.y + xc.y;
      t4v[jj].z = ow[jj].z + xa.z + xb.z + xc.z;
      t4v[jj].w = ow[jj].w + xa.w + xb.w + xc.w;
    }
#pragma unroll
    for (int jj = 0; jj < 4; ++jj) vp[jj] = t4v[jj];
  }
  wave_lds_sync();

  // phase 2: h = raw_own + S4[t+1] + S4[t+5] + S4[t+9] + S4[t+13]; emit all 8 rows
  if (outok) {
    const float4* p1  = (const float4*)(&Vw[lane + 1][0]);
    const float4* p5  = (const float4*)(&Vw[lane + 5][0]);
    const float4* p9  = (const float4*)(&Vw[lane + 9][0]);
    const float4* p13 = (const float4*)(&Vw[lane + 13][0]);
    float hA[SHB], hB[SHB];
#pragma unroll
    for (int jj = 0; jj < 4; ++jj) {
      float4 a4 = p1[jj];
      float4 b4 = p5[jj];
      float4 c4 = p9[jj];
      float4 d4 = p13[jj];
      hA[2*jj]     = ow[jj].x + a4.x + b4.x + c4.x + d4.x;
      hB[2*jj]     = ow[jj].y + a4.y + b4.y + c4.y + d4.y;
      hA[2*jj + 1] = ow[jj].z + a4.z + b4.z + c4.z + d4.z;
      hB[2*jj + 1] = ow[jj].w + a4.w + b4.w + c4.w + d4.w;
    }
#pragma unroll
    for (int j = 0; j < SHB; ++j) {
      const int r = r0 + j;
      const int nh = min(r + RR, HH - 1) - max(r - RR, 0) + 1;
      const float invN = 1.0f / (float)(nh * nw);
      float sumI;
      if (useSum) {
        sumI = sm[j];
      } else {
        const int off = r * WW + oc;
        const int chs = HH * WW;
        sumI = Ib[off] + Ib[chs + off] + Ib[2 * chs + off] + Ib[3 * chs + off];
      }
      q[((size_t)batch * HH + r) * WW + oc] = (hA[j] * sumI + hB[j]) * invN;
    }
  }
}

extern "C" void kernel_launch(void* const* d_in, const int* in_sizes, int n_in,
                              void* d_out, int out_size, void* d_ws, size_t ws_size,
                              hipStream_t stream) {
  const float* I = (const float*)d_in[0];   // (8,4,768,768) f32
  const float* p = (const float*)d_in[1];   // (8,1,768,768) f32
  float* q = (float*)d_out;                 // (8,1,768,768) f32

  const size_t npix = (size_t)BB * HH * WW;
  float2* AB = (float2*)d_ws;                               // 37.75 MB
  float* sumI_ws = (float*)(AB + npix);                     // +18.87 MB
  const size_t need = npix * sizeof(float2) + npix * sizeof(float);
  const int useSum = (ws_size >= need) ? 1 : 0;             // constant across calls

  dim3 gridA(NBANDA, NSTRIPEA, BB);    // (7, 48, 8)
  dim3 gridB(NBANDB, NSTRIPEB, BB);    // (8, 96, 8)
  hipLaunchKernelGGL(gf_stageA, gridA, dim3(TA), 0, stream, I, p, AB, sumI_ws, useSum);
  hipLaunchKernelGGL(gf_stageB, gridB, dim3(TB), 0, stream, I, AB, sumI_ws, q, useSum);
}

// Round 7
// 202.903 us; speedup vs baseline: 1.3673x; 1.1648x over previous
//
#include <hip/hip_runtime.h>

// GuidedFilterND: I (8,4,768,768) f32 guide, p (8,1,768,768) f32 input, r=8, eps=1e-4.
// Stage A: box-filter 19 product channels, per-pixel 4x4 SPD solve -> (As,b) float2 + sumI (ws)
// Stage B: box-filter (As,b); q = (f(As)*sumI + f(b)) / N
// Round 12: kill the tail quantization. Round-11's 16.8% occupancy = (10+0.5)/2 / 32:
//   supply 10.5 blocks/CU vs 10-block LDS cap (3 buffers x 80B x 64 = 15360B) ->
//   half-empty second round -> dispatch = 2x block time. Cross-round law verified:
//   stageA_time ~ (DS cycles per CU) / 0.7 x tail_factor.
//   Fix: FLAT 2-buffer scheme, 10240B -> 16-block cap >= 10.5 supply, single round.
//   Publish P (pair sums) + lo (even-col sums): 10W. One sync. Read 8 P-taps +
//   2 lo-taps: 50R. even = sum P[t-4..t+3] + lo[t+4]; odd = even - lo[t-4]
//   + P[t+4] - lo[t+4]. 60 DS/row, 2 syncs/row, no in-place hazards.
//   DS demand = 10.5 waves x 16 rows x 720cy = 121K cy/CU = 50us @100% -> ~72us @70%.
// Stage B: round-9 kernel but SINGLE-WAVE blocks (TB=64): supply 24 waves/CU now
//   fits residency (~28 by VGPR, 32 by LDS) -> fully resident, no tail. If stage B
//   was residency-bound it collapses; either way it finally shows in top-5 counters.

#define HH 768
#define WW 768
#define CC 4
#define BB 8
#define RR 8
#define EPSF 1.0e-4f

// ---- stage A geometry: 1 wave/block, 2 cols/lane (float2), flat 8-tap sum ----
#define TA 64
#define LN 64
#define OUTA 112             // output cols per wave (lanes 4..59, 2 each)
#define NBANDA 7             // ceil(768/112)
#define SHA 16
#define NSTRIPEA (HH / SHA)  // 48

// ---- stage B geometry: single-wave blocks ----
#define TB 64
#define OUTB 48              // output cols per wave
#define NBANDB (WW / OUTB)   // 16
#define SHB 8
#define NSTRIPEB (HH / SHB)  // 96

// Intra-wave LDS sync: wait this wave's own LDS ops (lgkm only; no vmcnt drain).
// "memory" clobber = compiler fence: no LDS access may be moved across it.
__device__ __forceinline__ void wave_lds_sync() {
  asm volatile("s_waitcnt lgkmcnt(0)" ::: "memory");
}

// Update both columns' 19-channel vertical sums from one row; returns per-col sumI.
template<bool ADD>
__device__ __forceinline__ float2 accum_pair(const float* __restrict__ Ib,
                                             const float* __restrict__ pb,
                                             int row, int col /*even*/,
                                             float* __restrict__ s0,
                                             float* __restrict__ s1) {
  const int off = row * WW + col;
  const int chs = HH * WW;
  float2 i0 = *(const float2*)(Ib + off);
  float2 i1 = *(const float2*)(Ib + chs + off);
  float2 i2 = *(const float2*)(Ib + 2 * chs + off);
  float2 i3 = *(const float2*)(Ib + 3 * chs + off);
  float2 pv = *(const float2*)(pb + off);
  float pr[19];
  // even column (x lane of the pair)
  pr[0] = i0.x; pr[1] = i1.x; pr[2] = i2.x; pr[3] = i3.x;
  pr[4] = pv.x;
  pr[5] = pv.x * i0.x; pr[6] = pv.x * i1.x; pr[7] = pv.x * i2.x; pr[8] = pv.x * i3.x;
  pr[9]  = i0.x * i0.x; pr[10] = i0.x * i1.x; pr[11] = i0.x * i2.x; pr[12] = i0.x * i3.x;
  pr[13] = i1.x * i1.x; pr[14] = i1.x * i2.x; pr[15] = i1.x * i3.x;
  pr[16] = i2.x * i2.x; pr[17] = i2.x * i3.x;
  pr[18] = i3.x * i3.x;
#pragma unroll
  for (int k = 0; k < 19; ++k) { if (ADD) s0[k] += pr[k]; else s0[k] -= pr[k]; }
  // odd column (y lane of the pair)
  pr[0] = i0.y; pr[1] = i1.y; pr[2] = i2.y; pr[3] = i3.y;
  pr[4] = pv.y;
  pr[5] = pv.y * i0.y; pr[6] = pv.y * i1.y; pr[7] = pv.y * i2.y; pr[8] = pv.y * i3.y;
  pr[9]  = i0.y * i0.y; pr[10] = i0.y * i1.y; pr[11] = i0.y * i2.y; pr[12] = i0.y * i3.y;
  pr[13] = i1.y * i1.y; pr[14] = i1.y * i2.y; pr[15] = i1.y * i3.y;
  pr[16] = i2.y * i2.y; pr[17] = i2.y * i3.y;
  pr[18] = i3.y * i3.y;
#pragma unroll
  for (int k = 0; k < 19; ++k) { if (ADD) s1[k] += pr[k]; else s1[k] -= pr[k]; }
  return make_float2(i0.x + i1.x + i2.x + i3.x, i0.y + i1.y + i2.y + i3.y);
}

__device__ __forceinline__ float2 gf_solve(const float* __restrict__ h, float invN) {
  float Im0 = h[0] * invN, Im1 = h[1] * invN, Im2 = h[2] * invN, Im3 = h[3] * invN;
  float pm = h[4] * invN;
  float ft0 = h[5] * invN - pm * Im0;
  float ft1 = h[6] * invN - pm * Im1;
  float ft2 = h[7] * invN - pm * Im2;
  float ft3 = h[8] * invN - pm * Im3;
  float m[4][4];
  m[0][0] = h[9]  * invN + EPSF;
  m[0][1] = h[10] * invN;
  m[0][2] = h[11] * invN;
  m[0][3] = h[12] * invN;
  m[1][1] = h[13] * invN + EPSF;
  m[1][2] = h[14] * invN;
  m[1][3] = h[15] * invN;
  m[2][2] = h[16] * invN + EPSF;
  m[2][3] = h[17] * invN;
  m[3][3] = h[18] * invN + EPSF;
  m[1][0] = m[0][1]; m[2][0] = m[0][2]; m[3][0] = m[0][3];
  m[2][1] = m[1][2]; m[3][1] = m[1][3]; m[3][2] = m[2][3];
  float y[4] = {1.0f, 1.0f, 1.0f, 1.0f};
#pragma unroll
  for (int k = 0; k < 4; ++k) {
    float piv = 1.0f / m[k][k];
#pragma unroll
    for (int j = 0; j < 4; ++j) m[k][j] *= piv;
    y[k] *= piv;
#pragma unroll
    for (int i = 0; i < 4; ++i) {
      if (i == k) continue;
      float f = m[i][k];
#pragma unroll
      for (int j = 0; j < 4; ++j) m[i][j] -= f * m[k][j];
      y[i] -= f * y[k];
    }
  }
  float Asum = ft0 * y[0] + ft1 * y[1] + ft2 * y[2] + ft3 * y[3];
  float bv = pm - Asum * (Im0 + Im1 + Im2 + Im3);
  return make_float2(Asum, bv);
}

__global__ __launch_bounds__(TA, 2) void gf_stageA(const float* __restrict__ I,
                                                   const float* __restrict__ p,
                                                   float2* __restrict__ AB,
                                                   float* __restrict__ sumI_ws,
                                                   int storeSum) {
  // two 20-float slots per lane (80 B rows, b128, conflict-free measured):
  // SP = pair sums P, SL = even-column (lo) sums. 10240 B total -> 16-block cap.
  __shared__ float SP[LN][20];
  __shared__ float SL[LN][20];
  const int t = threadIdx.x;
  const int band0 = (int)blockIdx.x * OUTA;   // first output col of this wave
  const int c0 = band0 - 8 + 2 * t;           // this lane's even col
  const bool ok = (c0 >= 0) && (c0 < WW);     // pair-granular (boundaries even)
  const int r0 = (int)blockIdx.y * SHA;
  const int batch = (int)blockIdx.z;

  const float* Ib = I + (size_t)batch * CC * HH * WW;
  const float* pb = p + (size_t)batch * HH * WW;
  float* sIb = sumI_ws + (size_t)batch * HH * WW;
  float2* ABb = AB + (size_t)batch * HH * WW;

  float s0[19], s1[19];
#pragma unroll
  for (int k = 0; k < 19; ++k) { s0[k] = 0.0f; s1[k] = 0.0f; }

  // warm-up: preload window of row (r0-1) = rows [r0-RR-1, r0+RR-1] clipped.
  {
    int rlo = r0 - RR - 1; if (rlo < 0) rlo = 0;
    for (int row = rlo; row < r0 + RR; ++row) {
      if (ok) {
        float2 f = accum_pair<true>(Ib, pb, row, c0, s0, s1);
        // rows 0..7 are only ever touched by stripe 0's warm-up: store sumI here
        if (storeSum && r0 == 0)
          *(float2*)(&sIb[row * WW + c0]) = f;
      }
    }
  }

  // output lanes: t in [4,59] emit cols e=band0-8+2t, o=e+1
  const int ec = c0;
  const bool outok = (t >= 4) && (t <= 59) && (ec < WW);
  const int nwe = min(ec + RR, WW - 1) - max(ec - RR, 0) + 1;
  const int nwo = min(ec + 1 + RR, WW - 1) - max(ec + 1 - RR, 0) + 1;

  for (int r = r0; r < r0 + SHA; ++r) {
    // vertical rolling update (float2: 10 loads/row total)
    {
      int rl = r + RR;
      if (rl < HH && ok) {
        float2 f = accum_pair<true>(Ib, pb, rl, c0, s0, s1);
        if (storeSum) *(float2*)(&sIb[rl * WW + c0]) = f;
      }
      int rt = r - RR - 1;
      if (rt >= 0 && ok) {
        accum_pair<false>(Ib, pb, rt, c0, s0, s1);
      }
    }
    // phase 0: publish P = s0+s1 and lo = s0 (10 x b128 writes)
    {
      float4* wp = (float4*)(&SP[t][0]);
      float4* wl = (float4*)(&SL[t][0]);
#pragma unroll
      for (int j = 0; j < 5; ++j) {
        float p0 = s0[4*j + 0] + s1[4*j + 0];
        float p1 = s0[4*j + 1] + s1[4*j + 1];
        float p2 = s0[4*j + 2] + s1[4*j + 2];
        float p3 = (4*j + 3 < 19) ? (s0[4*j + 3] + s1[4*j + 3]) : 0.0f;
        wp[j] = make_float4(p0, p1, p2, p3);
        wl[j] = make_float4(s0[4*j + 0], s0[4*j + 1], s0[4*j + 2],
                            (4*j + 3 < 19) ? s0[4*j + 3] : 0.0f);
      }
    }
    wave_lds_sync();
    // phase 1: flat 8-tap pair sum + 2 lo taps (50 x b128 reads), both outputs.
    //   even (col ec):   he = sum_{k=-4..+3} P[t+k]  + lo[t+4]
    //   odd  (col ec+1): ho = he - lo[t-4] + P[t+4] - lo[t+4]
    if (outok) {
      const float4* Pm4 = (const float4*)(&SP[t - 4][0]);
      const float4* Pm3 = (const float4*)(&SP[t - 3][0]);
      const float4* Pm2 = (const float4*)(&SP[t - 2][0]);
      const float4* Pm1 = (const float4*)(&SP[t - 1][0]);
      const float4* Pp1 = (const float4*)(&SP[t + 1][0]);
      const float4* Pp2 = (const float4*)(&SP[t + 2][0]);
      const float4* Pp3 = (const float4*)(&SP[t + 3][0]);
      const float4* Pp4 = (const float4*)(&SP[t + 4][0]);
      const float4* Lm4 = (const float4*)(&SL[t - 4][0]);
      const float4* Lp4 = (const float4*)(&SL[t + 4][0]);
      float he[20], ho[20];
#pragma unroll
      for (int j = 0; j < 5; ++j) {
        float4 a = Pm4[j], b = Pm3[j], c = Pm2[j], d = Pm1[j];
        float4 e = Pp1[j], f = Pp2[j], g = Pp3[j], hq = Pp4[j];
        float4 lm = Lm4[j], lp = Lp4[j];
        // own P recomputed from registers (not kept as an array)
        float o0 = s0[4*j + 0] + s1[4*j + 0];
        float o1 = s0[4*j + 1] + s1[4*j + 1];
        float o2 = s0[4*j + 2] + s1[4*j + 2];
        float o3 = (4*j + 3 < 19) ? (s0[4*j + 3] + s1[4*j + 3]) : 0.0f;
        float e0 = a.x + b.x + c.x + d.x + o0 + e.x + f.x + g.x + lp.x;
        float e1 = a.y + b.y + c.y + d.y + o1 + e.y + f.y + g.y + lp.y;
        float e2 = a.z + b.z + c.z + d.z + o2 + e.z + f.z + g.z + lp.z;
        float e3 = a.w + b.w + c.w + d.w + o3 + e.w + f.w + g.w + lp.w;
        he[4*j + 0] = e0; ho[4*j + 0] = e0 - lm.x + hq.x - lp.x;
        he[4*j + 1] = e1; ho[4*j + 1] = e1 - lm.y + hq.y - lp.y;
        he[4*j + 2] = e2; ho[4*j + 2] = e2 - lm.z + hq.z - lp.z;
        he[4*j + 3] = e3; ho[4*j + 3] = e3 - lm.w + hq.w - lp.w;
      }
      const int nh = min(r + RR, HH - 1) - max(r - RR, 0) + 1;
      float2 eo = gf_solve(he, 1.0f / (float)(nh * nwe));
      float2 oo = gf_solve(ho, 1.0f / (float)(nh * nwo));
      // packed store: (A_e, b_e, A_o, b_o) -> one dwordx4 (ec even => 16B aligned)
      *(float4*)(&ABb[(size_t)r * WW + ec]) = make_float4(eo.x, eo.y, oo.x, oo.y);
    }
    // loop-tail fence: next phase-0 writes must not hoist above this row's reads.
    wave_lds_sync();
  }
}

__global__ __launch_bounds__(TB, 4) void gf_stageB(const float* __restrict__ I,
                                                   const float2* __restrict__ AB,
                                                   const float* __restrict__ sumI_ws,
                                                   float* __restrict__ q, int useSum) {
  // single-wave block: [lane][row*2+ch], rows 0..7, padded to 20 floats (80 B)
  __shared__ float V[LN][20];
  const int lane = threadIdx.x;
  const int band0 = (int)blockIdx.x * OUTB;
  const int r0 = (int)blockIdx.y * SHB;
  const int batch = (int)blockIdx.z;
  const int gc = band0 - RR + lane;
  const bool colok = (gc >= 0 && gc < WW);

  const float2* ABb = AB + (size_t)batch * HH * WW;
  const float* sIb = sumI_ws + (size_t)batch * HH * WW;
  const float* Ib = I + (size_t)batch * CC * HH * WW;

  const int oc = band0 + lane;
  const bool outok = (lane < OUTB) && (oc < WW);
  const int nw = min(oc + RR, WW - 1) - max(oc - RR, 0) + 1;

  // burst-load the whole stripe's AB window: SHB+17 = 25 independent loads (MLP)
  float2 w[SHB + 17];
#pragma unroll
  for (int k = 0; k < SHB + 17; ++k) {
    const int row = r0 - RR - 1 + k;
    const bool okr = colok && (row >= 0) && (row < HH);
    w[k] = okr ? ABb[row * WW + gc] : make_float2(0.0f, 0.0f);
  }
  // burst-load sumI for the stripe's output pixels
  float sm[SHB];
  if (useSum) {
#pragma unroll
    for (int j = 0; j < SHB; ++j)
      sm[j] = outok ? sIb[(r0 + j) * WW + oc] : 0.0f;
  }

  // vertical running sums for ALL 8 rows, kept in registers
  float sA = 0.0f, sB = 0.0f;
#pragma unroll
  for (int k = 0; k < 17; ++k) { sA += w[k].x; sB += w[k].y; }
  float vsA[SHB], vsB[SHB];
#pragma unroll
  for (int j = 0; j < SHB; ++j) {
    sA += w[j + 17].x - w[j].x;
    sB += w[j + 17].y - w[j].y;
    vsA[j] = sA; vsB[j] = sB;
  }
  // pack own raw values: element (2j = A, 2j+1 = B)
  float4 ow[4];
#pragma unroll
  for (int jj = 0; jj < 4; ++jj)
    ow[jj] = make_float4(vsA[2*jj], vsB[2*jj], vsA[2*jj + 1], vsB[2*jj + 1]);

  // phase 0: publish all 8 rows at once (4 x b128)
  float4* vp = (float4*)(&V[lane][0]);
#pragma unroll
  for (int jj = 0; jj < 4; ++jj) vp[jj] = ow[jj];
  wave_lds_sync();

  // phase 1: in-place S4 (safe: writes depend on reads via dataflow)
  if (lane < LN - 3) {
    const float4* a1 = (const float4*)(&V[lane + 1][0]);
    const float4* a2 = (const float4*)(&V[lane + 2][0]);
    const float4* a3 = (const float4*)(&V[lane + 3][0]);
    float4 t4v[4];
#pragma unroll
    for (int jj = 0; jj < 4; ++jj) {
      float4 xa = a1[jj];
      float4 xb = a2[jj];
      float4 xc = a3[jj];
      t4v[jj].x = ow[jj].x + xa.x + xb.x + xc.x;
      t4v[jj].y = ow[jj].y + xa.y + xb.y + xc.y;
      t4v[jj].z = ow[jj].z + xa.z + xb.z + xc.z;
      t4v[jj].w = ow[jj].w + xa.w + xb.w + xc.w;
    }
#pragma unroll
    for (int jj = 0; jj < 4; ++jj) vp[jj] = t4v[jj];
  }
  wave_lds_sync();

  // phase 2: h = raw_own + S4[t+1] + S4[t+5] + S4[t+9] + S4[t+13]; emit all 8 rows
  if (outok) {
    const float4* p1  = (const float4*)(&V[lane + 1][0]);
    const float4* p5  = (const float4*)(&V[lane + 5][0]);
    const float4* p9  = (const float4*)(&V[lane + 9][0]);
    const float4* p13 = (const float4*)(&V[lane + 13][0]);
    float hA[SHB], hB[SHB];
#pragma unroll
    for (int jj = 0; jj < 4; ++jj) {
      float4 a4 = p1[jj];
      float4 b4 = p5[jj];
      float4 c4 = p9[jj];
      float4 d4 = p13[jj];
      hA[2*jj]     = ow[jj].x + a4.x + b4.x + c4.x + d4.x;
      hB[2*jj]     = ow[jj].y + a4.y + b4.y + c4.y + d4.y;
      hA[2*jj + 1] = ow[jj].z + a4.z + b4.z + c4.z + d4.z;
      hB[2*jj + 1] = ow[jj].w + a4.w + b4.w + c4.w + d4.w;
    }
#pragma unroll
    for (int j = 0; j < SHB; ++j) {
      const int r = r0 + j;
      const int nh = min(r + RR, HH - 1) - max(r - RR, 0) + 1;
      const float invN = 1.0f / (float)(nh * nw);
      float sumI;
      if (useSum) {
        sumI = sm[j];
      } else {
        const int off = r * WW + oc;
        const int chs = HH * WW;
        sumI = Ib[off] + Ib[chs + off] + Ib[2 * chs + off] + Ib[3 * chs + off];
      }
      q[((size_t)batch * HH + r) * WW + oc] = (hA[j] * sumI + hB[j]) * invN;
    }
  }
}

extern "C" void kernel_launch(void* const* d_in, const int* in_sizes, int n_in,
                              void* d_out, int out_size, void* d_ws, size_t ws_size,
                              hipStream_t stream) {
  const float* I = (const float*)d_in[0];   // (8,4,768,768) f32
  const float* p = (const float*)d_in[1];   // (8,1,768,768) f32
  float* q = (float*)d_out;                 // (8,1,768,768) f32

  const size_t npix = (size_t)BB * HH * WW;
  float2* AB = (float2*)d_ws;                               // 37.75 MB
  float* sumI_ws = (float*)(AB + npix);                     // +18.87 MB
  const size_t need = npix * sizeof(float2) + npix * sizeof(float);
  const int useSum = (ws_size >= need) ? 1 : 0;             // constant across calls

  dim3 gridA(NBANDA, NSTRIPEA, BB);    // (7, 48, 8)  = 2688 single-wave blocks
  dim3 gridB(NBANDB, NSTRIPEB, BB);    // (16, 96, 8) = 12288 single-wave blocks
  hipLaunchKernelGGL(gf_stageA, gridA, dim3(TA), 0, stream, I, p, AB, sumI_ws, useSum);
  hipLaunchKernelGGL(gf_stageB, gridB, dim3(TB), 0, stream, I, AB, sumI_ws, q, useSum);
}